// Round 1
// 264.885 us; speedup vs baseline: 1.0174x; 1.0174x over previous
//
#include <hip/hip_runtime.h>

// SpecNCutout: out = select(mask, mean(x), x)
// x: (B=128, H=256, W=1024, C=1) fp32. mask = union of 5 clipped rects/batch.
//
// R2 restructure: fold the x->out copy into the reduce pass (pass 1 streams
// read 128 MiB + write 128 MiB), then a hole-only fill pass writes `mean`
// into just the rect spans (~30 MiB, no re-read of x). Eliminates the
// separate finalize launch: each fill block privately sums the 2048
// partials with the EXACT same reduction tree as the old finalize_kernel,
// so the mean is bit-identical (absmax stayed 0.0 previously).
// Traffic: 384 MiB -> ~290 MiB; launches: 3 -> 2.

#define BB 128
#define HH 256
#define WW 1024
#define N_HOLES 5
#define HOLE_MINW (WW / 10)   // 102
#define HOLE_MINH (HH / 10)   // 25
#define N_ELEM (BB * HH * WW) // 33554432
#define RED_BLOCKS 2048
#define ROW_SLICES 8          // fill parallelism per hole

// Pass 1: streaming copy x->out while accumulating the global sum.
__global__ __launch_bounds__(256) void copy_reduce_kernel(
    const float* __restrict__ x, float* __restrict__ out,
    float* __restrict__ partials) {
  int tid = blockIdx.x * blockDim.x + threadIdx.x;
  int stride = gridDim.x * blockDim.x;          // 524288
  const float4* x4 = (const float4*)x;
  float4* out4 = (float4*)out;
  const int n4 = N_ELEM / 4;                    // 8388608
  float s = 0.0f;
  for (int i = tid; i < n4; i += stride) {      // 16 iters
    float4 v = x4[i];
    out4[i] = v;
    s += (v.x + v.y) + (v.z + v.w);
  }
  #pragma unroll
  for (int off = 32; off > 0; off >>= 1) s += __shfl_down(s, off, 64);
  __shared__ float wsum[4];
  int lane = threadIdx.x & 63;
  int wave = threadIdx.x >> 6;
  if (lane == 0) wsum[wave] = s;
  __syncthreads();
  if (threadIdx.x == 0)
    partials[blockIdx.x] = (wsum[0] + wsum[1]) + (wsum[2] + wsum[3]);
}

// Pass 2: write mean into hole spans only. One block per (batch, hole,
// row-slice). Each block first reduces the 2048 partials itself (8 KiB,
// L2-broadcast across blocks) using the identical tree as the old
// finalize_kernel -> bit-identical mean, no third launch, no stateful
// workspace (re-poison safe).
__global__ __launch_bounds__(256) void fill_holes_kernel(
    const int* __restrict__ xs, const int* __restrict__ ys,
    const int* __restrict__ xs_w_raw, const int* __restrict__ ys_h_raw,
    const float* __restrict__ act_rand,
    const float* __restrict__ partials,
    float* __restrict__ out) {
  float s = 0.0f;
  for (int i = threadIdx.x; i < RED_BLOCKS; i += 256) s += partials[i];
  #pragma unroll
  for (int off = 32; off > 0; off >>= 1) s += __shfl_down(s, off, 64);
  __shared__ float wsum[4];
  __shared__ float mean_sh;
  int lane = threadIdx.x & 63;
  int wave = threadIdx.x >> 6;
  if (lane == 0) wsum[wave] = s;
  __syncthreads();
  if (threadIdx.x == 0) {
    float t = (wsum[0] + wsum[1]) + (wsum[2] + wsum[3]);
    mean_sh = t * (1.0f / (float)N_ELEM);
  }
  __syncthreads();
  float mean = mean_sh;

  int bid = blockIdx.x;
  int b = bid / (N_HOLES * ROW_SLICES);
  int rem = bid % (N_HOLES * ROW_SLICES);
  int n = rem / ROW_SLICES;
  int slice = rem % ROW_SLICES;

  int base = b * N_HOLES + n;
  if (!(act_rand[base] < 1.0f)) return;          // PROB = 1.0, always true
  int cx = xs[base];
  int cy = ys[base];
  int hw = (xs_w_raw[base] + HOLE_MINW) >> 1;    // xs_w // 2 (positive)
  int hh = (ys_h_raw[base] + HOLE_MINH) >> 1;    // ys_h // 2
  int ys_s = min(max(cy - hh, 0), HH - 2);
  int ys_e = min(max(cy + hh, 1), HH - 1);
  int xs_s = min(max(cx - hw, 0), WW - 2);
  int xs_e = min(max(cx + hw, 1), WW - 1);

  // Overlapping holes double-write the same bit pattern: race-free.
  for (int h = ys_s + slice; h <= ys_e; h += ROW_SLICES) {
    long rowbase = (long)(b * HH + h) * WW;
    for (int w = xs_s + (int)threadIdx.x; w <= xs_e; w += 256) {
      out[rowbase + w] = mean;
    }
  }
}

extern "C" void kernel_launch(void* const* d_in, const int* in_sizes, int n_in,
                              void* d_out, int out_size, void* d_ws, size_t ws_size,
                              hipStream_t stream) {
  const float* x        = (const float*)d_in[0];
  const int* xs         = (const int*)d_in[1];
  const int* ys         = (const int*)d_in[2];
  const int* xs_w_raw   = (const int*)d_in[3];
  const int* ys_h_raw   = (const int*)d_in[4];
  const float* act_rand = (const float*)d_in[5];
  float* out = (float*)d_out;

  float* partials = (float*)d_ws;                // RED_BLOCKS floats

  copy_reduce_kernel<<<RED_BLOCKS, 256, 0, stream>>>(x, out, partials);
  fill_holes_kernel<<<BB * N_HOLES * ROW_SLICES, 256, 0, stream>>>(
      xs, ys, xs_w_raw, ys_h_raw, act_rand, partials, out);
}